// Round 2
// baseline (11711.442 us; speedup 1.0000x reference)
//
#include <hip/hip_runtime.h>
#include <math.h>

#define NB   32    // batch
#define TH   128   // scan steps
#define NL   6     // layers
#define DD   128   // model dim
#define NH   4     // heads
#define DHD  32    // head dim
#define TCAP 128   // max cached tokens (queries only go to i<=127)
#define D3   384
#define D4   512

typedef unsigned short u16;
typedef _Float16 f16;
typedef _Float16 f16x2 __attribute__((ext_vector_type(2)));

// fp32 -> fp16 (RNE) weight conversion into workspace
__global__ void prep_kernel(const float* __restrict__ qkv, const float* __restrict__ proj,
                            const float* __restrict__ fc,  const float* __restrict__ fc2,
                            f16* __restrict__ out) {
    int i = blockIdx.x * blockDim.x + threadIdx.x;
    const int n0 = NL * DD * D3, n1 = NL * DD * DD, n2 = NL * DD * D4, n3 = NL * D4 * DD;
    const int total = n0 + n1 + n2 + n3;
    if (i >= total) return;
    float v;
    if (i < n0)                 v = qkv[i];
    else if (i < n0 + n1)       v = proj[i - n0];
    else if (i < n0 + n1 + n2)  v = fc[i - n0 - n1];
    else                        v = fc2[i - n0 - n1 - n2];
    out[i] = (f16)v;
}

__device__ __forceinline__ float wave_xor_sum(float v) {
    #pragma unroll
    for (int off = 1; off < 64; off <<= 1) v += __shfl_xor(v, off);
    return v;
}
__device__ __forceinline__ float wave_xor_max(float v) {
    #pragma unroll
    for (int off = 1; off < 64; off <<= 1) v = fmaxf(v, __shfl_xor(v, off));
    return v;
}
__device__ __forceinline__ float gelu_tanh(float v) {
    float t = v * v * v;
    return 0.5f * v * (1.f + tanhf(0.7978845608028654f * (v + 0.044715f * t)));
}

// One workgroup (512 threads) per batch element; 128 KV-cached decode steps.
__global__ __launch_bounds__(512) void gpt_loop(
    const float* __restrict__ data,  const float* __restrict__ r,
    const float* __restrict__ wte_w, const float* __restrict__ wte_b,
    const float* __restrict__ wpe,
    const float* __restrict__ ln1_w, const float* __restrict__ ln1_b,
    const float* __restrict__ ln2_w, const float* __restrict__ ln2_b,
    const float* __restrict__ qkv_b, const float* __restrict__ proj_b,
    const float* __restrict__ fc_b,  const float* __restrict__ fc2_b,
    const float* __restrict__ lnf_w, const float* __restrict__ lnf_b,
    const float* __restrict__ head_w,const float* __restrict__ head_b,
    const f16* __restrict__ Wq, const f16* __restrict__ Wp,
    const f16* __restrict__ Wf, const f16* __restrict__ Wf2,
    f16* __restrict__ Kc, f16* __restrict__ Vc,
    float* __restrict__ Y)
{
    const int b    = blockIdx.x;
    const int tid  = threadIdx.x;
    const int lane = tid & 63;
    const int wid  = tid >> 6;

    __shared__ float x[DD], h[DD], qv[DD], o[DD], hmid[D4];
    __shared__ float sc[NH][TCAP];
    __shared__ float part[8][DD];
    __shared__ float s_state, u_state;
    __shared__ float c_ln1w[NL][DD], c_ln1b[NL][DD], c_ln2w[NL][DD], c_ln2b[NL][DD];
    __shared__ float c_qkvb[NL][D3], c_projb[NL][DD], c_fcb[NL][D4], c_fc2b[NL][DD];
    __shared__ float c_lnfw[DD], c_lnfb[DD], c_headw[DD], c_wte0[DD], c_wte1[DD], c_wteb[DD];

    const float p0 = data[b * 2 + 0];
    const float p1 = data[b * 2 + 1];
    const float hb = head_b[0];

    f16* Kb = Kc + (size_t)b * NL * TCAP * DD;
    f16* Vb = Vc + (size_t)b * NL * TCAP * DD;

    // ---- load parameter caches into LDS ----
    for (int idx = tid; idx < NL * DD; idx += 512) {
        int l = idx / DD, d = idx % DD;
        c_ln1w[l][d] = ln1_w[idx]; c_ln1b[l][d] = ln1_b[idx];
        c_ln2w[l][d] = ln2_w[idx]; c_ln2b[l][d] = ln2_b[idx];
        c_projb[l][d] = proj_b[idx]; c_fc2b[l][d] = fc2_b[idx];
    }
    for (int idx = tid; idx < NL * D3; idx += 512) c_qkvb[idx / D3][idx % D3] = qkv_b[idx];
    for (int idx = tid; idx < NL * D4; idx += 512) c_fcb[idx / D4][idx % D4] = fc_b[idx];
    if (tid < DD) {
        c_lnfw[tid] = lnf_w[tid]; c_lnfb[tid] = lnf_b[tid]; c_headw[tid] = head_w[tid];
        c_wte0[tid] = wte_w[tid]; c_wte1[tid] = wte_w[DD + tid]; c_wteb[tid] = wte_b[tid];
    }
    if (tid == 0) { s_state = 0.f; u_state = 0.f; }
    __syncthreads();

    for (int i = 0; i < TH; i++) {
        const float s  = s_state;
        const float uu = u_state;
        const float e  = r[b * TH + i] - s;

        if (tid < DD)
            x[tid] = e * c_wte0[tid] + uu * c_wte1[tid] + c_wteb[tid] + wpe[i * DD + tid];
        __syncthreads();

        for (int l = 0; l < NL; l++) {
            // ---- LN1 (all waves redundantly reduce; one barrier) ----
            {
                float v0 = x[lane], v1 = x[lane + 64];
                float sm = wave_xor_sum(v0 + v1);
                float sq = wave_xor_sum(v0 * v0 + v1 * v1);
                float m  = sm * (1.f / DD);
                float rs = rsqrtf(sq * (1.f / DD) - m * m + 1e-5f);
                if (tid < DD)
                    h[tid] = (x[tid] - m) * rs * c_ln1w[l][tid] + c_ln1b[l][tid];
            }
            __syncthreads();

            // ---- qkv matvec (384 cols as 192 column-pairs) ----
            f16* Krow = Kb + ((size_t)l * TCAP + i) * DD;
            f16* Vrow = Vb + ((size_t)l * TCAP + i) * DD;
            if (tid < 192) {
                const f16x2* W = (const f16x2*)(Wq + (size_t)l * DD * D3) + tid;
                float a0 = 0.f, a1 = 0.f;
                #pragma unroll 16
                for (int k = 0; k < DD; k++) {
                    f16x2 w = W[k * (D3 / 2)];
                    float hk = h[k];
                    a0 += hk * (float)w.x; a1 += hk * (float)w.y;
                }
                int c0 = 2 * tid;
                a0 += c_qkvb[l][c0]; a1 += c_qkvb[l][c0 + 1];
                if (c0 < DD)            { qv[c0] = a0; qv[c0 + 1] = a1; }
                else if (c0 < 2 * DD)   { f16x2 kv; kv.x = (f16)a0; kv.y = (f16)a1; *(f16x2*)(Krow + (c0 - DD)) = kv; }
                else                    { f16x2 vv; vv.x = (f16)a0; vv.y = (f16)a1; *(f16x2*)(Vrow + (c0 - 2 * DD)) = vv; }
            }
            __syncthreads();

            const f16* Kl = Kb + (size_t)l * TCAP * DD;
            const f16* Vl = Vb + (size_t)l * TCAP * DD;

            // ---- scores + softmax: wave w handles head w, probs -> sc ----
            if (wid < NH) {
                const int hh = wid;
                const float* qh = qv + hh * DHD;
                const bool ok0 = (lane <= i), ok1 = (lane + 64 <= i);
                const int j0 = ok0 ? lane : i;
                const int j1 = ok1 ? lane + 64 : i;
                const f16* K0 = Kl + (size_t)j0 * DD + hh * DHD;
                const f16* K1 = Kl + (size_t)j1 * DD + hh * DHD;
                float d0 = 0.f, d1 = 0.f;
                #pragma unroll
                for (int d2 = 0; d2 < DHD; d2++) {
                    float q = qh[d2];
                    d0 += q * (float)K0[d2];
                    d1 += q * (float)K1[d2];
                }
                const float sscale = 0.17677669529663687f;
                float s0 = ok0 ? d0 * sscale : -1e30f;
                float s1 = ok1 ? d1 * sscale : -1e30f;
                float mx = wave_xor_max(fmaxf(s0, s1));
                float e0 = ok0 ? expf(s0 - mx) : 0.f;
                float e1 = ok1 ? expf(s1 - mx) : 0.f;
                float inv = 1.f / wave_xor_sum(e0 + e1);
                sc[hh][lane]      = e0 * inv;
                sc[hh][lane + 64] = e1 * inv;
            }
            __syncthreads();

            // ---- AV partials: 512 threads = col(128) x j-strip(4) ----
            {
                int c = tid & 127, js = tid >> 7;
                int ja = js * 32, jbnd = min(i + 1, (js + 1) * 32);
                const f16* Vcp = Vl + c;
                float acc = 0.f;
                for (int j = ja; j < jbnd; j++)
                    acc += sc[c >> 5][j] * (float)Vcp[(size_t)j * DD];
                part[js][c] = acc;
            }
            __syncthreads();
            if (tid < DD) o[tid] = part[0][tid] + part[1][tid] + part[2][tid] + part[3][tid];
            __syncthreads();

            // ---- attn proj partials: 256 threads = colpair(64) x kq(4) ----
            if (tid < 256) {
                int p = tid & 63, kq = tid >> 6;
                const f16x2* W = (const f16x2*)(Wp + (size_t)l * DD * DD) + p;
                float a0 = 0.f, a1 = 0.f;
                #pragma unroll
                for (int k = kq * 32; k < kq * 32 + 32; k++) {
                    f16x2 w = W[k * (DD / 2)];
                    float ok = o[k];
                    a0 += ok * (float)w.x; a1 += ok * (float)w.y;
                }
                part[kq][2 * p] = a0; part[kq][2 * p + 1] = a1;
            }
            __syncthreads();
            if (tid < DD)
                x[tid] += part[0][tid] + part[1][tid] + part[2][tid] + part[3][tid] + c_projb[l][tid];
            __syncthreads();

            // ---- LN2 ----
            {
                float v0 = x[lane], v1 = x[lane + 64];
                float sm = wave_xor_sum(v0 + v1);
                float sq = wave_xor_sum(v0 * v0 + v1 * v1);
                float m  = sm * (1.f / DD);
                float rs = rsqrtf(sq * (1.f / DD) - m * m + 1e-5f);
                if (tid < DD)
                    h[tid] = (x[tid] - m) * rs * c_ln2w[l][tid] + c_ln2b[l][tid];
            }
            __syncthreads();

            // ---- fc (128->512) + gelu: 256 colpair threads ----
            if (tid < 256) {
                const f16x2* W = (const f16x2*)(Wf + (size_t)l * DD * D4) + tid;
                float a0 = 0.f, a1 = 0.f;
                #pragma unroll 16
                for (int k = 0; k < DD; k++) {
                    f16x2 w = W[k * (D4 / 2)];
                    float hk = h[k];
                    a0 += hk * (float)w.x; a1 += hk * (float)w.y;
                }
                int c0 = 2 * tid;
                a0 += c_fcb[l][c0]; a1 += c_fcb[l][c0 + 1];
                hmid[c0] = gelu_tanh(a0); hmid[c0 + 1] = gelu_tanh(a1);
            }
            __syncthreads();

            // ---- fc2 (512->128): 512 threads = colpair(64) x kchunk(8) ----
            {
                int p = tid & 63, ks = tid >> 6;
                const f16x2* W = (const f16x2*)(Wf2 + (size_t)l * D4 * DD) + p;
                float a0 = 0.f, a1 = 0.f;
                #pragma unroll 16
                for (int k = ks * 64; k < ks * 64 + 64; k++) {
                    f16x2 w = W[k * (DD / 2)];
                    float mk = hmid[k];
                    a0 += mk * (float)w.x; a1 += mk * (float)w.y;
                }
                part[ks][2 * p] = a0; part[ks][2 * p + 1] = a1;
            }
            __syncthreads();
            if (tid < DD) {
                float acc = c_fc2b[l][tid];
                #pragma unroll
                for (int q8 = 0; q8 < 8; q8++) acc += part[q8][tid];
                x[tid] += acc;
            }
            __syncthreads();
        } // layers

        // ---- final LN ----
        {
            float v0 = x[lane], v1 = x[lane + 64];
            float sm = wave_xor_sum(v0 + v1);
            float sq = wave_xor_sum(v0 * v0 + v1 * v1);
            float m  = sm * (1.f / DD);
            float rs = rsqrtf(sq * (1.f / DD) - m * m + 1e-5f);
            if (tid < DD)
                h[tid] = (x[tid] - m) * rs * c_lnfw[tid] + c_lnfb[tid];
        }
        __syncthreads();

        // ---- head + state update (wave 0) ----
        if (wid == 0) {
            float v = h[lane] * c_headw[lane] + h[lane + 64] * c_headw[lane + 64];
            v = wave_xor_sum(v);
            if (lane == 0) {
                float un = v + hb;
                Y[b * TH + i] = s;
                s_state = s + (-p0 * s + p1 * tanhf(un));
                u_state = un;
            }
        }
        __syncthreads();
    } // steps
}

extern "C" void kernel_launch(void* const* d_in, const int* in_sizes, int n_in,
                              void* d_out, int out_size, void* d_ws, size_t ws_size,
                              hipStream_t stream) {
    const float* data   = (const float*)d_in[0];
    const float* r      = (const float*)d_in[1];
    const float* wte_w  = (const float*)d_in[2];
    const float* wte_b  = (const float*)d_in[3];
    const float* wpe    = (const float*)d_in[4];
    const float* ln1_w  = (const float*)d_in[5];
    const float* ln1_b  = (const float*)d_in[6];
    const float* ln2_w  = (const float*)d_in[7];
    const float* ln2_b  = (const float*)d_in[8];
    const float* qkv_w  = (const float*)d_in[9];
    const float* qkv_b  = (const float*)d_in[10];
    const float* proj_w = (const float*)d_in[11];
    const float* proj_b = (const float*)d_in[12];
    const float* fc_w   = (const float*)d_in[13];
    const float* fc_b   = (const float*)d_in[14];
    const float* fc2_w  = (const float*)d_in[15];
    const float* fc2_b  = (const float*)d_in[16];
    const float* lnf_w  = (const float*)d_in[17];
    const float* lnf_b  = (const float*)d_in[18];
    const float* head_w = (const float*)d_in[19];
    const float* head_b = (const float*)d_in[20];

    f16* wsp = (f16*)d_ws;
    f16* Wq  = wsp;
    f16* Wp  = Wq  + NL * DD * D3;
    f16* Wf  = Wp  + NL * DD * DD;
    f16* Wf2 = Wf  + NL * DD * D4;
    f16* Kc  = Wf2 + NL * D4 * DD;
    f16* Vc  = Kc  + (size_t)NB * NL * TCAP * DD;

    const int n_w = NL * DD * D3 + NL * DD * DD + NL * DD * D4 + NL * D4 * DD;
    prep_kernel<<<(n_w + 255) / 256, 256, 0, stream>>>(qkv_w, proj_w, fc_w, fc2_w, Wq);

    gpt_loop<<<NB, 512, 0, stream>>>(
        data, r, wte_w, wte_b, wpe, ln1_w, ln1_b, ln2_w, ln2_b,
        qkv_b, proj_b, fc_b, fc2_b, lnf_w, lnf_b, head_w, head_b,
        Wq, Wp, Wf, Wf2, Kc, Vc, (float*)d_out);
}

// Round 3
// 10006.450 us; speedup vs baseline: 1.1704x; 1.1704x over previous
//
#include <hip/hip_runtime.h>
#include <math.h>

#define NB   32    // batch
#define TH   128   // scan steps
#define NL   6     // layers
#define DD   128   // model dim
#define NH   4     // heads
#define DHD  32    // head dim
#define TCAP 128   // max cached tokens
#define D3   384
#define D4   512

typedef _Float16 f16;
typedef _Float16 f16x2 __attribute__((ext_vector_type(2)));
typedef _Float16 f16x4 __attribute__((ext_vector_type(4)));
typedef _Float16 f16x8 __attribute__((ext_vector_type(8)));

// fp32 -> fp16 (RNE) weight conversion into workspace
__global__ void prep_kernel(const float* __restrict__ qkv, const float* __restrict__ proj,
                            const float* __restrict__ fc,  const float* __restrict__ fc2,
                            f16* __restrict__ out) {
    int i = blockIdx.x * blockDim.x + threadIdx.x;
    const int n0 = NL * DD * D3, n1 = NL * DD * DD, n2 = NL * DD * D4, n3 = NL * D4 * DD;
    const int total = n0 + n1 + n2 + n3;
    if (i >= total) return;
    float v;
    if (i < n0)                 v = qkv[i];
    else if (i < n0 + n1)       v = proj[i - n0];
    else if (i < n0 + n1 + n2)  v = fc[i - n0 - n1];
    else                        v = fc2[i - n0 - n1 - n2];
    out[i] = (f16)v;
}

__device__ __forceinline__ float wave_xor_sum(float v) {
    #pragma unroll
    for (int off = 1; off < 64; off <<= 1) v += __shfl_xor(v, off);
    return v;
}
__device__ __forceinline__ float wave_xor_max(float v) {
    #pragma unroll
    for (int off = 1; off < 64; off <<= 1) v = fmaxf(v, __shfl_xor(v, off));
    return v;
}
__device__ __forceinline__ float gelu_tanh(float v) {
    float t = v * v * v;
    return 0.5f * v * (1.f + tanhf(0.7978845608028654f * (v + 0.044715f * t)));
}

// One workgroup (512 threads) per batch element; 128 KV-cached decode steps.
// All weight matvecs: 16-B f16x8 loads, full 512-thread k-split, in-wave
// __shfl_xor reduction (k-split lives in lane bits above the column bits).
__global__ __launch_bounds__(512) void gpt_loop(
    const float* __restrict__ data,  const float* __restrict__ r,
    const float* __restrict__ wte_w, const float* __restrict__ wte_b,
    const float* __restrict__ wpe,
    const float* __restrict__ ln1_w, const float* __restrict__ ln1_b,
    const float* __restrict__ ln2_w, const float* __restrict__ ln2_b,
    const float* __restrict__ qkv_b, const float* __restrict__ proj_b,
    const float* __restrict__ fc_b,  const float* __restrict__ fc2_b,
    const float* __restrict__ lnf_w, const float* __restrict__ lnf_b,
    const float* __restrict__ head_w,const float* __restrict__ head_b,
    const f16* __restrict__ Wq, const f16* __restrict__ Wp,
    const f16* __restrict__ Wf, const f16* __restrict__ Wf2,
    f16* __restrict__ Kc, f16* __restrict__ Vc,
    float* __restrict__ Y)
{
    const int b    = blockIdx.x;
    const int tid  = threadIdx.x;
    const int lane = tid & 63;
    const int wid  = tid >> 6;

    __shared__ float x[DD], h[DD], qv[DD], o[DD], hmid[D4];
    __shared__ float sc[NH][TCAP];
    __shared__ float s_state, u_state;
    __shared__ float c_ln1w[NL][DD], c_ln1b[NL][DD], c_ln2w[NL][DD], c_ln2b[NL][DD];
    __shared__ float c_qkvb[NL][D3], c_projb[NL][DD], c_fcb[NL][D4], c_fc2b[NL][DD];
    __shared__ float c_lnfw[DD], c_lnfb[DD], c_headw[DD], c_wte0[DD], c_wte1[DD], c_wteb[DD];

    const float p0 = data[b * 2 + 0];
    const float p1 = data[b * 2 + 1];
    const float hb = head_b[0];

    f16* Kb = Kc + (size_t)b * NL * TCAP * DD;
    f16* Vb = Vc + (size_t)b * NL * TCAP * DD;

    for (int idx = tid; idx < NL * DD; idx += 512) {
        int l = idx / DD, d = idx % DD;
        c_ln1w[l][d] = ln1_w[idx]; c_ln1b[l][d] = ln1_b[idx];
        c_ln2w[l][d] = ln2_w[idx]; c_ln2b[l][d] = ln2_b[idx];
        c_projb[l][d] = proj_b[idx]; c_fc2b[l][d] = fc2_b[idx];
    }
    for (int idx = tid; idx < NL * D3; idx += 512) c_qkvb[idx / D3][idx % D3] = qkv_b[idx];
    for (int idx = tid; idx < NL * D4; idx += 512) c_fcb[idx / D4][idx % D4] = fc_b[idx];
    if (tid < DD) {
        c_lnfw[tid] = lnf_w[tid]; c_lnfb[tid] = lnf_b[tid]; c_headw[tid] = head_w[tid];
        c_wte0[tid] = wte_w[tid]; c_wte1[tid] = wte_w[DD + tid]; c_wteb[tid] = wte_b[tid];
    }
    if (tid == 0) { s_state = 0.f; u_state = 0.f; }
    __syncthreads();

    for (int i = 0; i < TH; i++) {
        const float s  = s_state;
        const float uu = u_state;
        const float e  = r[b * TH + i] - s;

        if (tid < DD)
            x[tid] = e * c_wte0[tid] + uu * c_wte1[tid] + c_wteb[tid] + wpe[i * DD + tid];
        __syncthreads();

        for (int l = 0; l < NL; l++) {
            // ---- LN1 ----
            {
                float v0 = x[lane], v1 = x[lane + 64];
                float sm = wave_xor_sum(v0 + v1);
                float sq = wave_xor_sum(v0 * v0 + v1 * v1);
                float m  = sm * (1.f / DD);
                float rs = rsqrtf(sq * (1.f / DD) - m * m + 1e-5f);
                if (tid < DD)
                    h[tid] = (x[tid] - m) * rs * c_ln1w[l][tid] + c_ln1b[l][tid];
            }
            __syncthreads();

            // ---- qkv (128x384): 6 waves, 8 cols x 8 k-splits per lane ----
            f16* Krow = Kb + ((size_t)l * TCAP + i) * DD;
            f16* Vrow = Vb + ((size_t)l * TCAP + i) * DD;
            if (wid < 6) {
                const int cg = lane & 7;       // col-group in wave
                const int ks = lane >> 3;      // k-split 0..7 (k-chunk of 16)
                const int cb = wid * 64 + cg * 8;
                const f16* W = Wq + (size_t)l * DD * D3 + cb;
                const int k0 = ks * 16;
                float acc[8] = {0,0,0,0,0,0,0,0};
                #pragma unroll
                for (int k = 0; k < 16; k++) {
                    f16x8 w = *(const f16x8*)(W + (size_t)(k0 + k) * D3);
                    float hk = h[k0 + k];
                    #pragma unroll
                    for (int j = 0; j < 8; j++) acc[j] += hk * (float)w[j];
                }
                #pragma unroll
                for (int off = 8; off <= 32; off <<= 1) {
                    #pragma unroll
                    for (int j = 0; j < 8; j++) acc[j] += __shfl_xor(acc[j], off);
                }
                if (ks == 0) {
                    if (cb < DD) {
                        #pragma unroll
                        for (int j = 0; j < 8; j++) qv[cb + j] = acc[j] + c_qkvb[l][cb + j];
                    } else if (cb < 2 * DD) {
                        f16x8 kv;
                        #pragma unroll
                        for (int j = 0; j < 8; j++) kv[j] = (f16)(acc[j] + c_qkvb[l][cb + j]);
                        *(f16x8*)(Krow + (cb - DD)) = kv;
                    } else {
                        f16x8 vv;
                        #pragma unroll
                        for (int j = 0; j < 8; j++) vv[j] = (f16)(acc[j] + c_qkvb[l][cb + j]);
                        *(f16x8*)(Vrow + (cb - 2 * DD)) = vv;
                    }
                }
            }
            __syncthreads();

            const f16* Kl = Kb + (size_t)l * TCAP * DD;
            const f16* Vl = Vb + (size_t)l * TCAP * DD;

            // ---- scores + softmax: wave w = head w; 16-B K loads ----
            if (wid < NH) {
                const int hh = wid;
                const bool ok0 = (lane <= i), ok1 = (lane + 64 <= i);
                const int j0 = ok0 ? lane : i;
                const int j1 = ok1 ? lane + 64 : i;
                const f16x8* K0 = (const f16x8*)(Kl + (size_t)j0 * DD + hh * DHD);
                const f16x8* K1 = (const f16x8*)(Kl + (size_t)j1 * DD + hh * DHD);
                float d0 = 0.f, d1 = 0.f;
                #pragma unroll
                for (int g = 0; g < 4; g++) {
                    f16x8 ka = K0[g], kb2 = K1[g];
                    #pragma unroll
                    for (int t = 0; t < 8; t++) {
                        float q = qv[hh * DHD + g * 8 + t];
                        d0 += q * (float)ka[t];
                        d1 += q * (float)kb2[t];
                    }
                }
                const float sscale = 0.17677669529663687f;
                float s0 = ok0 ? d0 * sscale : -1e30f;
                float s1 = ok1 ? d1 * sscale : -1e30f;
                float mx = wave_xor_max(fmaxf(s0, s1));
                float e0 = ok0 ? expf(s0 - mx) : 0.f;
                float e1 = ok1 ? expf(s1 - mx) : 0.f;
                float inv = 1.f / wave_xor_sum(e0 + e1);
                sc[hh][lane]      = e0 * inv;
                sc[hh][lane + 64] = e1 * inv;
            }
            __syncthreads();

            // ---- AV: 32 col-quads x 16 j-splits, in-wave reduce ----
            {
                const int qd = wid * 4 + (lane & 3);   // col-quad 0..31
                const int js = lane >> 2;              // j-split 0..15
                const int cb = qd * 4;
                const int hh = cb >> 5;
                const f16* Vp = Vl + cb;
                float a0 = 0.f, a1 = 0.f, a2 = 0.f, a3 = 0.f;
                const int ja = js * 8, jbnd = min(i + 1, js * 8 + 8);
                for (int j = ja; j < jbnd; j++) {
                    f16x4 vv = *(const f16x4*)(Vp + (size_t)j * DD);
                    float p = sc[hh][j];
                    a0 += p * (float)vv[0]; a1 += p * (float)vv[1];
                    a2 += p * (float)vv[2]; a3 += p * (float)vv[3];
                }
                #pragma unroll
                for (int off = 4; off <= 32; off <<= 1) {
                    a0 += __shfl_xor(a0, off); a1 += __shfl_xor(a1, off);
                    a2 += __shfl_xor(a2, off); a3 += __shfl_xor(a3, off);
                }
                if (js == 0) { o[cb] = a0; o[cb + 1] = a1; o[cb + 2] = a2; o[cb + 3] = a3; }
            }
            __syncthreads();

            // ---- attn proj (128x128): 16 col-groups x 32 k-splits ----
            {
                const int cg2 = lane & 1;
                const int ks  = lane >> 1;             // 0..31, k-chunk of 4
                const int cb  = (wid * 2 + cg2) * 8;
                const f16* W = Wp + (size_t)l * DD * DD + cb;
                const int k0 = ks * 4;
                float acc[8] = {0,0,0,0,0,0,0,0};
                #pragma unroll
                for (int k = 0; k < 4; k++) {
                    f16x8 w = *(const f16x8*)(W + (size_t)(k0 + k) * DD);
                    float ok = o[k0 + k];
                    #pragma unroll
                    for (int j = 0; j < 8; j++) acc[j] += ok * (float)w[j];
                }
                #pragma unroll
                for (int off = 2; off <= 32; off <<= 1) {
                    #pragma unroll
                    for (int j = 0; j < 8; j++) acc[j] += __shfl_xor(acc[j], off);
                }
                if (ks == 0) {
                    #pragma unroll
                    for (int j = 0; j < 8; j++) x[cb + j] += acc[j] + c_projb[l][cb + j];
                }
            }
            __syncthreads();

            // ---- LN2 ----
            {
                float v0 = x[lane], v1 = x[lane + 64];
                float sm = wave_xor_sum(v0 + v1);
                float sq = wave_xor_sum(v0 * v0 + v1 * v1);
                float m  = sm * (1.f / DD);
                float rs = rsqrtf(sq * (1.f / DD) - m * m + 1e-5f);
                if (tid < DD)
                    h[tid] = (x[tid] - m) * rs * c_ln2w[l][tid] + c_ln2b[l][tid];
            }
            __syncthreads();

            // ---- fc (128x512) + gelu: 64 col-groups x 8 k-splits ----
            {
                const int cg = lane & 7;
                const int ks = lane >> 3;              // k-chunk of 16
                const int cb = wid * 64 + cg * 8;
                const f16* W = Wf + (size_t)l * DD * D4 + cb;
                const int k0 = ks * 16;
                float acc[8] = {0,0,0,0,0,0,0,0};
                #pragma unroll
                for (int k = 0; k < 16; k++) {
                    f16x8 w = *(const f16x8*)(W + (size_t)(k0 + k) * D4);
                    float hk = h[k0 + k];
                    #pragma unroll
                    for (int j = 0; j < 8; j++) acc[j] += hk * (float)w[j];
                }
                #pragma unroll
                for (int off = 8; off <= 32; off <<= 1) {
                    #pragma unroll
                    for (int j = 0; j < 8; j++) acc[j] += __shfl_xor(acc[j], off);
                }
                if (ks == 0) {
                    #pragma unroll
                    for (int j = 0; j < 8; j++) hmid[cb + j] = gelu_tanh(acc[j] + c_fcb[l][cb + j]);
                }
            }
            __syncthreads();

            // ---- fc2 (512x128): 16 col-groups x 32 k-splits ----
            {
                const int cg2 = lane & 1;
                const int ks  = lane >> 1;             // 0..31, k-chunk of 16
                const int cb  = (wid * 2 + cg2) * 8;
                const f16* W = Wf2 + (size_t)l * D4 * DD + cb;
                const int k0 = ks * 16;
                float acc[8] = {0,0,0,0,0,0,0,0};
                #pragma unroll
                for (int k = 0; k < 16; k++) {
                    f16x8 w = *(const f16x8*)(W + (size_t)(k0 + k) * DD);
                    float mk = hmid[k0 + k];
                    #pragma unroll
                    for (int j = 0; j < 8; j++) acc[j] += mk * (float)w[j];
                }
                #pragma unroll
                for (int off = 2; off <= 32; off <<= 1) {
                    #pragma unroll
                    for (int j = 0; j < 8; j++) acc[j] += __shfl_xor(acc[j], off);
                }
                if (ks == 0) {
                    #pragma unroll
                    for (int j = 0; j < 8; j++) x[cb + j] += acc[j] + c_fc2b[l][cb + j];
                }
            }
            __syncthreads();
        } // layers

        // ---- final LN ----
        {
            float v0 = x[lane], v1 = x[lane + 64];
            float sm = wave_xor_sum(v0 + v1);
            float sq = wave_xor_sum(v0 * v0 + v1 * v1);
            float m  = sm * (1.f / DD);
            float rs = rsqrtf(sq * (1.f / DD) - m * m + 1e-5f);
            if (tid < DD)
                h[tid] = (x[tid] - m) * rs * c_lnfw[tid] + c_lnfb[tid];
        }
        __syncthreads();

        // ---- head + state update (wave 0) ----
        if (wid == 0) {
            float v = h[lane] * c_headw[lane] + h[lane + 64] * c_headw[lane + 64];
            v = wave_xor_sum(v);
            if (lane == 0) {
                float un = v + hb;
                Y[b * TH + i] = s;
                s_state = s + (-p0 * s + p1 * tanhf(un));
                u_state = un;
            }
        }
        __syncthreads();
    } // steps
}

extern "C" void kernel_launch(void* const* d_in, const int* in_sizes, int n_in,
                              void* d_out, int out_size, void* d_ws, size_t ws_size,
                              hipStream_t stream) {
    const float* data   = (const float*)d_in[0];
    const float* r      = (const float*)d_in[1];
    const float* wte_w  = (const float*)d_in[2];
    const float* wte_b  = (const float*)d_in[3];
    const float* wpe    = (const float*)d_in[4];
    const float* ln1_w  = (const float*)d_in[5];
    const float* ln1_b  = (const float*)d_in[6];
    const float* ln2_w  = (const float*)d_in[7];
    const float* ln2_b  = (const float*)d_in[8];
    const float* qkv_w  = (const float*)d_in[9];
    const float* qkv_b  = (const float*)d_in[10];
    const float* proj_w = (const float*)d_in[11];
    const float* proj_b = (const float*)d_in[12];
    const float* fc_w   = (const float*)d_in[13];
    const float* fc_b   = (const float*)d_in[14];
    const float* fc2_w  = (const float*)d_in[15];
    const float* fc2_b  = (const float*)d_in[16];
    const float* lnf_w  = (const float*)d_in[17];
    const float* lnf_b  = (const float*)d_in[18];
    const float* head_w = (const float*)d_in[19];
    const float* head_b = (const float*)d_in[20];

    f16* wsp = (f16*)d_ws;
    f16* Wq  = wsp;
    f16* Wp  = Wq  + NL * DD * D3;
    f16* Wf  = Wp  + NL * DD * DD;
    f16* Wf2 = Wf  + NL * DD * D4;
    f16* Kc  = Wf2 + NL * D4 * DD;
    f16* Vc  = Kc  + (size_t)NB * NL * TCAP * DD;

    const int n_w = NL * DD * D3 + NL * DD * DD + NL * DD * D4 + NL * D4 * DD;
    prep_kernel<<<(n_w + 255) / 256, 256, 0, stream>>>(qkv_w, proj_w, fc_w, fc2_w, Wq);

    gpt_loop<<<NB, 512, 0, stream>>>(
        data, r, wte_w, wte_b, wpe, ln1_w, ln1_b, ln2_w, ln2_b,
        qkv_b, proj_b, fc_b, fc2_b, lnf_w, lnf_b, head_w, head_b,
        Wq, Wp, Wf, Wf2, Kc, Vc, (float*)d_out);
}